// Round 8
// baseline (236.341 us; speedup 1.0000x reference)
//
#include <hip/hip_runtime.h>
#include <hip/hip_bf16.h>
#include <hip/hip_cooperative_groups.h>

namespace cg = cooperative_groups;

using f32x4 = __attribute__((ext_vector_type(4))) float;
using s16x8 = __attribute__((ext_vector_type(8))) short;
using s16x4 = __attribute__((ext_vector_type(4))) short;

__device__ inline unsigned short f2bf(float x) {
    __hip_bfloat16 b = __float2bfloat16(x);      // RNE
    return __builtin_bit_cast(unsigned short, b);
}
__device__ inline float bf2f(unsigned short u) {
    unsigned int t = ((unsigned int)u) << 16;
    return __builtin_bit_cast(float, t);
}
__device__ inline f32x4 mfma16(s16x8 a, s16x8 b, f32x4 c) {
    return __builtin_amdgcn_mfma_f32_16x16x32_bf16(a, b, c, 0, 0, 0);
}
// async global->LDS, 16B per lane; LDS dest = wave-uniform base + lane*16.
__device__ inline void gload16(const unsigned short* g, unsigned short* l) {
    __builtin_amdgcn_global_load_lds(
        (const __attribute__((address_space(1))) void*)g,
        (__attribute__((address_space(3))) void*)l, 16, 0, 0);
}

// Pre-swizzle convention (G21): for every staged [rows][128]-bf16 buffer,
// 16B-chunk c of row r is stored in global at chunk slot (c ^ (key&7)),
// key == reader's tile-local row (tile bases ≡0 mod 8 rows). Readers
// global_load_lds LINEARLY and ds_read with the same XOR.

// ---------------------------------------------------------------------------
// Cooperative mega-kernel: grid 256 x 512, 1 block/CU.
//  Phase 0 (convert): WP via LDS transpose (blocks 0..15); Ut + tbl (16..255).
//  Phase 1 (ht):      h/t = leaky(state@W+b) + hw/tw dots (blocks 0..254).
//  Phase 2 (main):    out = (h U) t^T + hw + tw + tbl, hU in-LDS.
// ---------------------------------------------------------------------------
__global__ __launch_bounds__(512) void mega_k(
    const float* __restrict__ state,
    const float* __restrict__ head_w, const float* __restrict__ tail_w,
    const float* __restrict__ U, const float* __restrict__ wtab,
    const float* __restrict__ cls_w, const float* __restrict__ cls_b,
    const float* __restrict__ head_b, const float* __restrict__ tail_b,
    unsigned short* __restrict__ WP, unsigned short* __restrict__ Ut,
    unsigned short* __restrict__ hbuf, unsigned short* __restrict__ tbuf,
    float* __restrict__ hwp, float* __restrict__ twp,
    float* __restrict__ tblp, float* __restrict__ out)
{
    cg::grid_group grid = cg::this_grid();
    __shared__ __align__(16) char smem[124416];
    const int tid = threadIdx.x;
    const int blk = blockIdx.x;
    const int w = tid >> 6, lane = tid & 63;
    const int l16 = lane & 15, kq = lane >> 4;

    // ======================= phase 0: convert =======================
    if (blk < 16) {
        unsigned short (*Lw)[258] = (unsigned short (*)[258])smem;  // 33 KB
        const int ks = blk;
        for (int idx = tid; idx < 64 * 16; idx += 512) {     // zero pad cols
            int r = idx >> 4, c = idx & 15;
            Lw[r][120 + ((c >= 8) ? 128 : 0) + (c & 7)] = 0;
        }
        for (int idx = tid; idx < 7680; idx += 512) {
            int r = idx / 120, c = idx - r * 120;
            Lw[r][c] = f2bf(head_w[(ks * 64 + r) * 120 + c]);
        }
        for (int idx = tid; idx < 7680; idx += 512) {
            int r = idx / 120, c = idx - r * 120;
            Lw[r][128 + c] = f2bf(tail_w[(ks * 64 + r) * 120 + c]);
        }
        __syncthreads();
        for (int item = tid; item < 2048; item += 512) {
            int n = item >> 3, kcp = item & 7;
            int kc = kcp ^ (n & 7);
            s16x8 v;
            #pragma unroll
            for (int e = 0; e < 8; ++e) v[e] = (short)Lw[kc * 8 + e][n];
            *(s16x8*)&WP[ks * 16384 + item * 8] = v;
        }
    } else {
        for (int idx = (blk - 16) * 512 + tid; idx < 166400; idx += 240 * 512) {
            if (idx < 163840) {
                int j = idx & 127, i2 = (idx >> 7) & 127, o = idx >> 14;
                float v = (i2 < 120 && j < 120) ? U[((size_t)o * 120 + i2) * 120 + j] : 0.f;
                Ut[(size_t)o * 16384 + (size_t)j * 128 + i2] = f2bf(v);
            } else {
                int id = idx - 163840;
                int p = id / 10, o = id - (id / 10) * 10;
                float s = 0.f;
                #pragma unroll
                for (int wq = 0; wq < 20; ++wq)
                    s += wtab[p * 20 + wq] * cls_w[o * 262 + 242 + wq];
                tblp[p * 12 + o] = s;
            }
        }
    }
    __threadfence();
    grid.sync();

    // ======================= phase 1: ht =======================
    if (blk < 255) {
        // LDS: Ss[2] @ 0 (2x4KB), Ws[2] @ 8192 (2x32KB)
        unsigned short* Ss0 = (unsigned short*)smem;
        unsigned short* Ss1 = (unsigned short*)(smem + 4096);
        unsigned short* Ws0 = (unsigned short*)(smem + 8192);
        unsigned short* Ws1 = (unsigned short*)(smem + 8192 + 32768);
        unsigned short* SsA[2] = {Ss0, Ss1};
        unsigned short* WsA[2] = {Ws0, Ws1};
        const int r0 = blk * 32;
        const int srow = (tid >> 3) & 31, skc = tid & 7;
        const bool do_s = tid < 256;
        const float* sp = &state[(size_t)(r0 + srow) * 1024 + skc * 8];

        f32x4 acc[2][2];
        #pragma unroll
        for (int fn = 0; fn < 2; ++fn)
            #pragma unroll
            for (int fr = 0; fr < 2; ++fr) acc[fn][fr] = (f32x4){0.f, 0.f, 0.f, 0.f};

        #pragma unroll
        for (int j = 0; j < 4; ++j) {
            int off = (w * 4 + j) * 512;
            gload16(WP + off + lane * 8, &Ws0[off]);
        }
        if (do_s) {
            f32x4 a0 = *(const f32x4*)sp;
            f32x4 a1 = *(const f32x4*)(sp + 4);
            s16x8 pk;
            #pragma unroll
            for (int e = 0; e < 4; ++e) { pk[e] = (short)f2bf(a0[e]); pk[e + 4] = (short)f2bf(a1[e]); }
            *(s16x8*)((char*)Ss0 + srow * 128 + ((skc * 16) ^ ((srow & 7) << 4))) = pk;
        }
        __syncthreads();

        for (int it = 0; it < 16; ++it) {
            const int cur = it & 1;
            f32x4 a0, a1;
            if (it < 15) {
                #pragma unroll
                for (int j = 0; j < 4; ++j) {
                    int off = (w * 4 + j) * 512;
                    gload16(WP + (it + 1) * 16384 + off + lane * 8, &WsA[cur ^ 1][off]);
                }
                if (do_s) {
                    a0 = *(const f32x4*)(sp + (it + 1) * 64);
                    a1 = *(const f32x4*)(sp + (it + 1) * 64 + 4);
                }
            }
            const char* SsB = (const char*)SsA[cur];
            const char* WsB = (const char*)WsA[cur];
            s16x8 bf[2][2];
            #pragma unroll
            for (int fr = 0; fr < 2; ++fr) {
                int rr = fr * 16 + l16;
                #pragma unroll
                for (int ks = 0; ks < 2; ++ks)
                    bf[fr][ks] = *(const s16x8*)(SsB + rr * 128 + ((ks * 64 + kq * 16) ^ ((rr & 7) << 4)));
            }
            #pragma unroll
            for (int fn = 0; fn < 2; ++fn) {
                int n = w * 32 + fn * 16 + l16;
                #pragma unroll
                for (int ks = 0; ks < 2; ++ks) {
                    s16x8 af = *(const s16x8*)(WsB + n * 128 + ((ks * 64 + kq * 16) ^ ((n & 7) << 4)));
                    #pragma unroll
                    for (int fr = 0; fr < 2; ++fr)
                        acc[fn][fr] = mfma16(af, bf[fr][ks], acc[fn][fr]);
                }
            }
            if (it < 15 && do_s) {
                s16x8 pk;
                #pragma unroll
                for (int e = 0; e < 4; ++e) { pk[e] = (short)f2bf(a0[e]); pk[e + 4] = (short)f2bf(a1[e]); }
                *(s16x8*)((char*)SsA[cur ^ 1] + srow * 128 + ((skc * 16) ^ ((srow & 7) << 4))) = pk;
            }
            __syncthreads();
        }

        // epilogue: bias + leaky -> swizzled LDS tiles + hbuf/tbuf global
        unsigned short* Hl = Ws0;                     // [32][128] key r&7
        unsigned short* Tl = Ws1;                     // [32][128] key r&7
        #pragma unroll
        for (int fn = 0; fn < 2; ++fn) {
            const int n0 = w * 32 + fn * 16 + kq * 4;
            const int isT = n0 >= 128;
            const int c0 = n0 & 127;
            const int g = c0 >> 3, sub = c0 & 7;
            const float* bp = isT ? tail_b : head_b;
            unsigned short* dstl = isT ? Tl : Hl;
            unsigned short* dstg = isT ? tbuf : hbuf;
            #pragma unroll
            for (int fr = 0; fr < 2; ++fr) {
                const int rloc = fr * 16 + l16;
                const int r = r0 + rloc;
                s16x4 pk;
                #pragma unroll
                for (int e = 0; e < 4; ++e) {
                    float bv = (c0 + e < 120) ? bp[c0 + e] : 0.f;
                    float z = acc[fn][fr][e] + bv;
                    z = (z >= 0.f) ? z : 0.01f * z;
                    pk[e] = (short)f2bf(z);
                }
                *(s16x4*)&dstl[rloc * 128 + ((g ^ (rloc & 7)) << 3) + sub] = pk;
                {
                    int bq = r / 255, x = r - bq * 255;
                    *(s16x4*)&dstg[((size_t)bq * 256 + x) * 128 + ((g ^ (x & 7)) << 3) + sub] = pk;
                }
            }
        }
        __syncthreads();

        float* Wl = (float*)(Ws0 + 4096);   // 2430 f32 after Hl's 8KB
        for (int idx = tid; idx < 2430; idx += 512) {
            if (idx < 2420) {
                int which = idx / 1210, rem = idx - which * 1210;
                int o = rem / 121, i = rem - o * 121;
                Wl[idx] = cls_w[o * 262 + which * 121 + i];
            } else Wl[idx] = cls_b[idx - 2420];
        }
        __syncthreads();

        for (int d = tid; d < 640; d += 512) {
            int which = d / 320, rem = d - which * 320;
            int rr = rem / 10, o = rem - rr * 10;
            const unsigned short* row = (which ? Tl : Hl) + rr * 128;
            const float* wp2 = &Wl[which * 1210 + o * 121];
            float s = 0.f;
            #pragma unroll
            for (int c = 0; c < 15; ++c) {
                s16x8 v = *(const s16x8*)&row[(c ^ (rr & 7)) << 3];
                #pragma unroll
                for (int e = 0; e < 8; ++e)
                    s += bf2f((unsigned short)v[e]) * wp2[c * 8 + e];
            }
            s += wp2[120];
            int gr = r0 + rr;
            if (!which) hwp[(size_t)gr * 12 + o] = s + Wl[2420 + o];
            else        twp[(size_t)gr * 12 + o] = s;
        }
    }
    __threadfence();
    grid.sync();

    // ======================= phase 2: main =======================
    {
        unsigned short* hUs = (unsigned short*)smem;          // 384 x 256B = 96K
        unsigned short* Bs  = (unsigned short*)smem;          // alias: 64K
        unsigned short* Hs  = (unsigned short*)(smem + 65536);// alias: 8K
        float* Ts = (float*)(smem + 98304);                   // tw (3060)
        float* Tb = (float*)(smem + 110592);                  // tbl (3072)
        float* Hw = (float*)(smem + 122880);                  // hw (384)

        const int virt = (blk & 7) * 32 + (blk >> 3);   // XCD k <- b in [4k,4k+4)
        const int b = virt >> 3, mg = virt & 7;
        const int wm = w >> 2, wy = w & 3;
        const size_t tbase = (size_t)b * 256 * 128;
        const size_t hbase = ((size_t)b * 256 + mg * 32) * 128;

        #pragma unroll
        for (int j = 0; j < 8; ++j) {
            int off = (w * 8 + j) * 512;
            gload16(&tbuf[tbase + off + lane * 8], &Bs[off]);
        }
        gload16(&hbuf[hbase + (size_t)(w * 64 + lane) * 8], &Hs[w * 512]);
        {
            const float* twb = twp + (size_t)b * 3060;
            for (int idx = tid; idx < 3060; idx += 512) Ts[idx] = twb[idx];
            for (int idx = tid; idx < 3072; idx += 512) Tb[idx] = tblp[idx];
            if (tid < 384) {
                int mgl = mg * 384 + tid;
                Hw[tid] = (mgl < 3060) ? hwp[(size_t)b * 3060 + mgl] : 0.f;
            }
        }
        __syncthreads();

        s16x8 bfr[4][4];   // [ks][fy]
        #pragma unroll
        for (int ks = 0; ks < 4; ++ks)
            #pragma unroll
            for (int fy = 0; fy < 4; ++fy) {
                int row = wy * 64 + fy * 16 + l16;
                bfr[ks][fy] = *(const s16x8*)((const char*)Bs + row * 256 +
                               ((ks * 64 + kq * 16) ^ ((row & 7) << 4)));
            }
        s16x8 bh[2][4];    // [xf][ks]
        #pragma unroll
        for (int xf = 0; xf < 2; ++xf) {
            int rr = xf * 16 + l16;
            #pragma unroll
            for (int ks = 0; ks < 4; ++ks)
                bh[xf][ks] = *(const s16x8*)((const char*)Hs + rr * 256 +
                              ((ks * 64 + kq * 16) ^ ((rr & 7) << 4)));
        }
        __syncthreads();   // staging reads done; hUs region now writable

        // phase 2a: hU tile -> LDS (wave w owns j in [w*16, w*16+16))
        {
            const int jrow = w * 16 + l16;
            const int j0 = w * 16 + kq * 4;
            const int g2 = j0 >> 3, sub2b = (j0 & 7) * 2;
            #pragma unroll 2
            for (int o = 0; o < 10; ++o) {
                f32x4 acc1[2];
                acc1[0] = (f32x4){0.f, 0.f, 0.f, 0.f};
                acc1[1] = (f32x4){0.f, 0.f, 0.f, 0.f};
                #pragma unroll
                for (int ks = 0; ks < 4; ++ks) {
                    s16x8 af = *(const s16x8*)&Ut[(size_t)o * 16384 +
                                (size_t)jrow * 128 + ks * 32 + kq * 8];
                    acc1[0] = mfma16(af, bh[0][ks], acc1[0]);
                    acc1[1] = mfma16(af, bh[1][ks], acc1[1]);
                }
                #pragma unroll
                for (int xf = 0; xf < 2; ++xf) {
                    int mloc = (xf * 16 + l16) * 12 + o;
                    s16x4 pk;
                    #pragma unroll
                    for (int e = 0; e < 4; ++e) pk[e] = (short)f2bf(acc1[xf][e]);
                    *(s16x4*)((char*)hUs + mloc * 256 +
                              ((g2 ^ (mloc & 7)) << 4) + sub2b) = pk;
                }
            }
        }
        __syncthreads();

        // phase 2b: 3 m-tiles of 128, A from LDS, fused epilogue
        for (int i = 0; i < 3; ++i) {
            const int mt = i * 128;
            f32x4 acc[4][4];
            #pragma unroll
            for (int fm = 0; fm < 4; ++fm)
                #pragma unroll
                for (int fy = 0; fy < 4; ++fy) acc[fm][fy] = (f32x4){0.f, 0.f, 0.f, 0.f};

            __builtin_amdgcn_s_setprio(1);
            #pragma unroll
            for (int ks = 0; ks < 4; ++ks) {
                s16x8 af[4];
                #pragma unroll
                for (int fm = 0; fm < 4; ++fm) {
                    int row = mt + wm * 64 + fm * 16 + l16;
                    af[fm] = *(const s16x8*)((const char*)hUs + row * 256 +
                              ((ks * 64 + kq * 16) ^ ((row & 7) << 4)));
                }
                #pragma unroll
                for (int fm = 0; fm < 4; ++fm)
                    #pragma unroll
                    for (int fy = 0; fy < 4; ++fy)
                        acc[fm][fy] = mfma16(af[fm], bfr[ks][fy], acc[fm][fy]);
            }
            __builtin_amdgcn_s_setprio(0);

            #pragma unroll
            for (int fm = 0; fm < 4; ++fm) {
                const int mloc = mt + wm * 64 + fm * 16 + kq * 4;
                const int xloc = mloc / 12, o0 = mloc % 12;   // o0 in {0,4,8}
                const int x = mg * 32 + xloc;
                if (x < 255) {
                    const int rx = b * 255 + x;
                    f32x4 hv = *(const f32x4*)&Hw[xloc * 12 + o0];
                    #pragma unroll
                    for (int fy = 0; fy < 4; ++fy) {
                        const int y = wy * 64 + fy * 16 + l16;
                        if (y < 255) {
                            f32x4 tv = *(const f32x4*)&Ts[y * 12 + o0];
                            int p = y - x + 1; if (p < 0) p = 0;
                            f32x4 wv = *(const f32x4*)&Tb[p * 12 + o0];
                            float* op = &out[((size_t)rx * 255 + y) * 10 + o0];
                            if (o0 < 8) {
                                float v[4];
                                #pragma unroll
                                for (int e = 0; e < 4; ++e)
                                    v[e] = acc[fm][fy][e] + hv[e] + tv[e] + wv[e];
                                __builtin_memcpy(op, v, 16);
                            } else {
                                float v[2];
                                v[0] = acc[fm][fy][0] + hv[0] + tv[0] + wv[0];
                                v[1] = acc[fm][fy][1] + hv[1] + tv[1] + wv[1];
                                __builtin_memcpy(op, v, 8);
                            }
                        }
                    }
                }
            }
        }
    }
}

// ---------------------------------------------------------------------------
extern "C" void kernel_launch(void* const* d_in, const int* in_sizes, int n_in,
                              void* d_out, int out_size, void* d_ws, size_t ws_size,
                              hipStream_t stream)
{
    (void)in_sizes; (void)n_in; (void)out_size; (void)ws_size;
    const float* state  = (const float*)d_in[0];
    const float* head_w = (const float*)d_in[1];
    const float* head_b = (const float*)d_in[2];
    const float* tail_w = (const float*)d_in[3];
    const float* tail_b = (const float*)d_in[4];
    const float* U      = (const float*)d_in[5];
    const float* wtab   = (const float*)d_in[6];
    const float* cls_w  = (const float*)d_in[7];
    const float* cls_b  = (const float*)d_in[8];
    float* out = (float*)d_out;

    unsigned short* u16 = (unsigned short*)d_ws;
    unsigned short* tbuf = u16;                    // 32*256*128 = 1048576
    unsigned short* hbuf = tbuf + 1048576;         // 32*256*128 = 1048576
    unsigned short* WP   = hbuf + 1048576;         // 16*256*64  = 262144
    unsigned short* Ut   = WP + 262144;            // 10*128*128 = 163840
    float* hwp  = (float*)(Ut + 163840);           // 8160*12
    float* twp  = hwp + 97920;
    float* tblp = twp + 97920;                     // 256*12

    void* args[] = {
        (void*)&state, (void*)&head_w, (void*)&tail_w, (void*)&U,
        (void*)&wtab, (void*)&cls_w, (void*)&cls_b,
        (void*)&head_b, (void*)&tail_b,
        (void*)&WP, (void*)&Ut, (void*)&hbuf, (void*)&tbuf,
        (void*)&hwp, (void*)&twp, (void*)&tblp, (void*)&out
    };
    hipLaunchCooperativeKernel((const void*)mega_k, dim3(256), dim3(512),
                               args, 0, stream);
}

// Round 9
// 75.733 us; speedup vs baseline: 3.1207x; 3.1207x over previous
//
#include <hip/hip_runtime.h>
#include <hip/hip_bf16.h>

using f32x4 = __attribute__((ext_vector_type(4))) float;
using s16x8 = __attribute__((ext_vector_type(8))) short;
using s16x4 = __attribute__((ext_vector_type(4))) short;

__device__ inline unsigned short f2bf(float x) {
    __hip_bfloat16 b = __float2bfloat16(x);      // RNE
    return __builtin_bit_cast(unsigned short, b);
}
__device__ inline float bf2f(unsigned short u) {
    unsigned int t = ((unsigned int)u) << 16;
    return __builtin_bit_cast(float, t);
}
__device__ inline f32x4 mfma16(s16x8 a, s16x8 b, f32x4 c) {
    return __builtin_amdgcn_mfma_f32_16x16x32_bf16(a, b, c, 0, 0, 0);
}
// async global->LDS, 16B per lane; LDS dest = wave-uniform base + lane*16.
__device__ inline void gload16(const unsigned short* g, unsigned short* l) {
    __builtin_amdgcn_global_load_lds(
        (const __attribute__((address_space(1))) void*)g,
        (__attribute__((address_space(3))) void*)l, 16, 0, 0);
}

// Pre-swizzle convention (G21): for every staged [rows][128]-bf16 buffer,
// 16B-chunk c of row r is stored in global at chunk slot (c ^ (key&7)),
// key == reader's tile-local row (tile bases ≡0 mod 8 rows). Readers
// global_load_lds LINEARLY and ds_read with the same XOR.

// ---------------------------------------------------------------------------
// K0: WP [kstep 16][n 256][kc' 8][e 8] bf16 via LDS transpose (16 blocks).
// Ut/tblp conversion now lives in ht_mfma's prologue.
// ---------------------------------------------------------------------------
__global__ __launch_bounds__(256) void convert_wp(
    const float* __restrict__ head_w, const float* __restrict__ tail_w,
    unsigned short* __restrict__ WP)
{
    const int tid = threadIdx.x;
    __shared__ unsigned short Lw[64][258];    // padded pitch: conflict-light
    const int ks = blockIdx.x;
    for (int idx = tid; idx < 64 * 16; idx += 256) {    // zero pad cols
        int r = idx >> 4, c = idx & 15;
        Lw[r][120 + ((c >= 8) ? 128 : 0) + (c & 7)] = 0;
    }
    for (int idx = tid; idx < 7680; idx += 256) {
        int r = idx / 120, c = idx - r * 120;
        Lw[r][c] = f2bf(head_w[(ks * 64 + r) * 120 + c]);
    }
    for (int idx = tid; idx < 7680; idx += 256) {
        int r = idx / 120, c = idx - r * 120;
        Lw[r][128 + c] = f2bf(tail_w[(ks * 64 + r) * 120 + c]);
    }
    __syncthreads();
    for (int item = tid; item < 2048; item += 256) {
        int n = item >> 3, kcp = item & 7;
        int kc = kcp ^ (n & 7);
        s16x8 v;
        #pragma unroll
        for (int e = 0; e < 8; ++e) v[e] = (short)Lw[kc * 8 + e][n];
        *(s16x8*)&WP[ks * 16384 + item * 8] = v;
    }
}

// ---------------------------------------------------------------------------
// K1: h/t = leaky(state @ W + b), head+tail fused; prologue also converts
// Ut + tblp (grid-strided); epilogue stores hbuf/tbuf (pre-swizzled) and
// computes the hw/tw cls_w dots. 512 thr / 8 waves, grid 255 (r-tile 32).
// ---------------------------------------------------------------------------
__global__ __launch_bounds__(512) void ht_mfma(
    const float* __restrict__ state, const unsigned short* __restrict__ WP,
    const float* __restrict__ U, const float* __restrict__ wtab,
    const float* __restrict__ head_b, const float* __restrict__ tail_b,
    const float* __restrict__ cls_w, const float* __restrict__ cls_b,
    unsigned short* __restrict__ Ut,
    unsigned short* __restrict__ hbuf, unsigned short* __restrict__ tbuf,
    float* __restrict__ hwp, float* __restrict__ twp, float* __restrict__ tblp)
{
    __shared__ unsigned short Ss[2][32 * 64];     //  2 x 4 KB: state tile bf16
    __shared__ unsigned short Ws[2][256 * 64];    //  2 x 32 KB: both W tiles
    const int r0 = blockIdx.x * 32;
    const int tid = threadIdx.x;
    const int w = tid >> 6, lane = tid & 63;
    const int l16 = lane & 15, kq = lane >> 4;
    const int srow = (tid >> 3) & 31, skc = tid & 7;
    const bool do_s = tid < 256;
    const float* sp = &state[(size_t)(r0 + srow) * 1024 + skc * 8];

    f32x4 acc[2][2];
    #pragma unroll
    for (int fn = 0; fn < 2; ++fn)
        #pragma unroll
        for (int fr = 0; fr < 2; ++fr) acc[fn][fr] = (f32x4){0.f, 0.f, 0.f, 0.f};

    // prologue: stage iter 0, plus grid-strided Ut/tblp conversion
    #pragma unroll
    for (int j = 0; j < 4; ++j) {
        int off = (w * 4 + j) * 512;
        gload16(WP + off + lane * 8, &Ws[0][off]);
    }
    if (do_s) {
        f32x4 a0 = *(const f32x4*)sp;
        f32x4 a1 = *(const f32x4*)(sp + 4);
        s16x8 pk;
        #pragma unroll
        for (int e = 0; e < 4; ++e) { pk[e] = (short)f2bf(a0[e]); pk[e + 4] = (short)f2bf(a1[e]); }
        *(s16x8*)((char*)&Ss[0][0] + srow * 128 + ((skc * 16) ^ ((srow & 7) << 4))) = pk;
    }
    for (int idx = blockIdx.x * 512 + tid; idx < 166400; idx += 255 * 512) {
        if (idx < 163840) {
            int j = idx & 127, i2 = (idx >> 7) & 127, o = idx >> 14;  // j fastest
            float v = (i2 < 120 && j < 120) ? U[((size_t)o * 120 + i2) * 120 + j] : 0.f;
            Ut[(size_t)o * 16384 + (size_t)j * 128 + i2] = f2bf(v);
        } else {
            int id = idx - 163840;
            int p = id / 10, o = id - (id / 10) * 10;
            float s = 0.f;
            #pragma unroll
            for (int wq = 0; wq < 20; ++wq)
                s += wtab[p * 20 + wq] * cls_w[o * 262 + 242 + wq];
            tblp[p * 12 + o] = s;
        }
    }
    __syncthreads();

    for (int it = 0; it < 16; ++it) {
        const int cur = it & 1;
        f32x4 a0, a1;
        if (it < 15) {
            #pragma unroll
            for (int j = 0; j < 4; ++j) {
                int off = (w * 4 + j) * 512;
                gload16(WP + (it + 1) * 16384 + off + lane * 8, &Ws[cur ^ 1][off]);
            }
            if (do_s) {
                a0 = *(const f32x4*)(sp + (it + 1) * 64);
                a1 = *(const f32x4*)(sp + (it + 1) * 64 + 4);
            }
        }
        const char* SsB = (const char*)&Ss[cur][0];
        const char* WsB = (const char*)&Ws[cur][0];
        s16x8 bf[2][2];
        #pragma unroll
        for (int fr = 0; fr < 2; ++fr) {
            int rr = fr * 16 + l16;
            #pragma unroll
            for (int ks = 0; ks < 2; ++ks)
                bf[fr][ks] = *(const s16x8*)(SsB + rr * 128 + ((ks * 64 + kq * 16) ^ ((rr & 7) << 4)));
        }
        #pragma unroll
        for (int fn = 0; fn < 2; ++fn) {
            int n = w * 32 + fn * 16 + l16;
            #pragma unroll
            for (int ks = 0; ks < 2; ++ks) {
                s16x8 af = *(const s16x8*)(WsB + n * 128 + ((ks * 64 + kq * 16) ^ ((n & 7) << 4)));
                #pragma unroll
                for (int fr = 0; fr < 2; ++fr)
                    acc[fn][fr] = mfma16(af, bf[fr][ks], acc[fn][fr]);
            }
        }
        if (it < 15 && do_s) {
            s16x8 pk;
            #pragma unroll
            for (int e = 0; e < 4; ++e) { pk[e] = (short)f2bf(a0[e]); pk[e + 4] = (short)f2bf(a1[e]); }
            *(s16x8*)((char*)&Ss[cur ^ 1][0] + srow * 128 + ((skc * 16) ^ ((srow & 7) << 4))) = pk;
        }
        __syncthreads();
    }

    // ---- epilogue: bias + leaky -> swizzled LDS tiles + hbuf/tbuf global ----
    unsigned short* Hl = &Ws[0][0];                   // [32][128] key r&7
    unsigned short* Tl = &Ws[1][0];                   // [32][128] key r&7
    #pragma unroll
    for (int fn = 0; fn < 2; ++fn) {
        const int n0 = w * 32 + fn * 16 + kq * 4;     // wave-uniform isT
        const int isT = n0 >= 128;
        const int c0 = n0 & 127;
        const int g = c0 >> 3, sub = c0 & 7;
        const float* bp = isT ? tail_b : head_b;
        unsigned short* dstl = isT ? Tl : Hl;
        unsigned short* dstg = isT ? tbuf : hbuf;
        #pragma unroll
        for (int fr = 0; fr < 2; ++fr) {
            const int rloc = fr * 16 + l16;
            const int r = r0 + rloc;
            s16x4 pk;
            #pragma unroll
            for (int e = 0; e < 4; ++e) {
                float bv = (c0 + e < 120) ? bp[c0 + e] : 0.f;
                float z = acc[fn][fr][e] + bv;
                z = (z >= 0.f) ? z : 0.01f * z;
                pk[e] = (short)f2bf(z);
            }
            *(s16x4*)&dstl[rloc * 128 + ((g ^ (rloc & 7)) << 3) + sub] = pk;
            {
                int bq = r / 255, x = r - bq * 255;
                *(s16x4*)&dstg[((size_t)bq * 256 + x) * 128 + ((g ^ (x & 7)) << 3) + sub] = pk;
            }
        }
    }
    __syncthreads();

    // stage cls_w slices for the hw/tw dots
    float* Wl = (float*)&Ws[0][4096];     // 2430 f32: [which][o][121] + cls_b[10]
    for (int idx = tid; idx < 2430; idx += 512) {
        if (idx < 2420) {
            int which = idx / 1210, rem = idx - which * 1210;
            int o = rem / 121, i = rem - o * 121;
            Wl[idx] = cls_w[o * 262 + which * 121 + i];
        } else Wl[idx] = cls_b[idx - 2420];
    }
    __syncthreads();

    for (int d = tid; d < 640; d += 512) {
        int which = d / 320, rem = d - which * 320;
        int rr = rem / 10, o = rem - rr * 10;
        const unsigned short* row = (which ? Tl : Hl) + rr * 128;
        const float* wp2 = &Wl[which * 1210 + o * 121];
        float s = 0.f;
        #pragma unroll
        for (int c = 0; c < 15; ++c) {
            s16x8 v = *(const s16x8*)&row[(c ^ (rr & 7)) << 3];
            #pragma unroll
            for (int e = 0; e < 8; ++e)
                s += bf2f((unsigned short)v[e]) * wp2[c * 8 + e];
        }
        s += wp2[120];                                 // "ones" column
        int gr = r0 + rr;
        if (!which) hwp[(size_t)gr * 12 + o] = s + Wl[2420 + o];
        else        twp[(size_t)gr * 12 + o] = s;
    }
}

// ---------------------------------------------------------------------------
// K4: out = (h U) t^T + hw + tw + tbl, hU computed IN-KERNEL (no hUb buffer).
// grid 256 (XCD-remapped), 512 thr / 8 waves (phase2: 2m x 4y).
// ---------------------------------------------------------------------------
__global__ __launch_bounds__(512) void main_mfma(
    const unsigned short* __restrict__ hbuf, const unsigned short* __restrict__ tbuf,
    const unsigned short* __restrict__ Ut,
    const float* __restrict__ hwp, const float* __restrict__ twp,
    const float* __restrict__ tblp, float* __restrict__ out)
{
    __shared__ __align__(16) char smem[124416];
    unsigned short* hUs = (unsigned short*)smem;          // 384 rows x 256B = 96K
    unsigned short* Bs  = (unsigned short*)smem;          // alias: 64K staging
    unsigned short* Hs  = (unsigned short*)(smem + 65536);// alias: 8K staging
    float* Ts = (float*)(smem + 98304);                   // tw rows of b (3060)
    float* Tb = (float*)(smem + 110592);                  // tbl (3072)
    float* Hw = (float*)(smem + 122880);                  // hw (384)

    const int wgid = blockIdx.x + (blockIdx.y << 3);
    const int virt = (wgid & 7) * 32 + (wgid >> 3);       // XCD k <- b in [4k,4k+4)
    const int b = virt >> 3, mg = virt & 7;
    const int tid = threadIdx.x;
    const int w = tid >> 6, lane = tid & 63;
    const int l16 = lane & 15, kq = lane >> 4;
    const int wm = w >> 2, wy = w & 3;
    const size_t tbase = (size_t)b * 256 * 128;
    const size_t hbase = ((size_t)b * 256 + mg * 32) * 128;

    // ---- phase 0: staging ----
    #pragma unroll
    for (int j = 0; j < 8; ++j) {
        int off = (w * 8 + j) * 512;
        gload16(&tbuf[tbase + off + lane * 8], &Bs[off]);
    }
    gload16(&hbuf[hbase + (size_t)(w * 64 + lane) * 8], &Hs[w * 512]);
    {
        const float* twb = twp + (size_t)b * 3060;
        for (int idx = tid; idx < 3060; idx += 512) Ts[idx] = twb[idx];
        for (int idx = tid; idx < 3072; idx += 512) Tb[idx] = tblp[idx];
        if (tid < 384) {
            int mgl = mg * 384 + tid;
            Hw[tid] = (mgl < 3060) ? hwp[(size_t)b * 3060 + mgl] : 0.f;
        }
    }
    __syncthreads();

    // hoist t fragments (phase-2 B) and h fragments (phase-1 B) to registers
    s16x8 bfr[4][4];   // [ks][fy]
    #pragma unroll
    for (int ks = 0; ks < 4; ++ks)
        #pragma unroll
        for (int fy = 0; fy < 4; ++fy) {
            int row = wy * 64 + fy * 16 + l16;
            bfr[ks][fy] = *(const s16x8*)((const char*)Bs + row * 256 +
                           ((ks * 64 + kq * 16) ^ ((row & 7) << 4)));
        }
    s16x8 bh[2][4];    // [xf][ks]
    #pragma unroll
    for (int xf = 0; xf < 2; ++xf) {
        int rr = xf * 16 + l16;
        #pragma unroll
        for (int ks = 0; ks < 4; ++ks)
            bh[xf][ks] = *(const s16x8*)((const char*)Hs + rr * 256 +
                          ((ks * 64 + kq * 16) ^ ((rr & 7) << 4)));
    }
    __syncthreads();   // all staging reads done; hUs region now writable

    // ---- phase 1: hU tile -> LDS (wave w owns j in [w*16, w*16+16)) ----
    {
        const int jrow = w * 16 + l16;
        const int j0 = w * 16 + kq * 4;
        const int g2 = j0 >> 3, sub2b = (j0 & 7) * 2;     // byte sub-offset
        #pragma unroll 2
        for (int o = 0; o < 10; ++o) {
            f32x4 acc1[2];
            acc1[0] = (f32x4){0.f, 0.f, 0.f, 0.f};
            acc1[1] = (f32x4){0.f, 0.f, 0.f, 0.f};
            #pragma unroll
            for (int ks = 0; ks < 4; ++ks) {
                s16x8 af = *(const s16x8*)&Ut[(size_t)o * 16384 +
                            (size_t)jrow * 128 + ks * 32 + kq * 8];
                acc1[0] = mfma16(af, bh[0][ks], acc1[0]);
                acc1[1] = mfma16(af, bh[1][ks], acc1[1]);
            }
            #pragma unroll
            for (int xf = 0; xf < 2; ++xf) {
                int mloc = (xf * 16 + l16) * 12 + o;
                s16x4 pk;
                #pragma unroll
                for (int e = 0; e < 4; ++e) pk[e] = (short)f2bf(acc1[xf][e]);
                *(s16x4*)((char*)hUs + mloc * 256 +
                          ((g2 ^ (mloc & 7)) << 4) + sub2b) = pk;
            }
        }
    }
    __syncthreads();

    // ---- phase 2: 3 m-tiles of 128, A from LDS, fused epilogue ----
    for (int i = 0; i < 3; ++i) {
        const int mt = i * 128;
        f32x4 acc[4][4];
        #pragma unroll
        for (int fm = 0; fm < 4; ++fm)
            #pragma unroll
            for (int fy = 0; fy < 4; ++fy) acc[fm][fy] = (f32x4){0.f, 0.f, 0.f, 0.f};

        __builtin_amdgcn_s_setprio(1);
        #pragma unroll
        for (int ks = 0; ks < 4; ++ks) {
            s16x8 af[4];
            #pragma unroll
            for (int fm = 0; fm < 4; ++fm) {
                int row = mt + wm * 64 + fm * 16 + l16;
                af[fm] = *(const s16x8*)((const char*)hUs + row * 256 +
                          ((ks * 64 + kq * 16) ^ ((row & 7) << 4)));
            }
            #pragma unroll
            for (int fm = 0; fm < 4; ++fm)
                #pragma unroll
                for (int fy = 0; fy < 4; ++fy)
                    acc[fm][fy] = mfma16(af[fm], bfr[ks][fy], acc[fm][fy]);
        }
        __builtin_amdgcn_s_setprio(0);

        #pragma unroll
        for (int fm = 0; fm < 4; ++fm) {
            const int mloc = mt + wm * 64 + fm * 16 + kq * 4;
            const int xloc = mloc / 12, o0 = mloc % 12;   // o0 in {0,4,8}
            const int x = mg * 32 + xloc;
            if (x < 255) {
                const int rx = b * 255 + x;
                f32x4 hv = *(const f32x4*)&Hw[xloc * 12 + o0];
                #pragma unroll
                for (int fy = 0; fy < 4; ++fy) {
                    const int y = wy * 64 + fy * 16 + l16;
                    if (y < 255) {
                        f32x4 tv = *(const f32x4*)&Ts[y * 12 + o0];
                        int p = y - x + 1; if (p < 0) p = 0;
                        f32x4 wv = *(const f32x4*)&Tb[p * 12 + o0];
                        float* op = &out[((size_t)rx * 255 + y) * 10 + o0];
                        if (o0 < 8) {
                            float v[4];
                            #pragma unroll
                            for (int e = 0; e < 4; ++e)
                                v[e] = acc[fm][fy][e] + hv[e] + tv[e] + wv[e];
                            __builtin_memcpy(op, v, 16);
                        } else {
                            float v[2];
                            v[0] = acc[fm][fy][0] + hv[0] + tv[0] + wv[0];
                            v[1] = acc[fm][fy][1] + hv[1] + tv[1] + wv[1];
                            __builtin_memcpy(op, v, 8);
                        }
                    }
                }
            }
        }
    }
}

// ---------------------------------------------------------------------------
extern "C" void kernel_launch(void* const* d_in, const int* in_sizes, int n_in,
                              void* d_out, int out_size, void* d_ws, size_t ws_size,
                              hipStream_t stream)
{
    (void)in_sizes; (void)n_in; (void)out_size; (void)ws_size;
    const float* state  = (const float*)d_in[0];
    const float* head_w = (const float*)d_in[1];
    const float* head_b = (const float*)d_in[2];
    const float* tail_w = (const float*)d_in[3];
    const float* tail_b = (const float*)d_in[4];
    const float* U      = (const float*)d_in[5];
    const float* wtab   = (const float*)d_in[6];
    const float* cls_w  = (const float*)d_in[7];
    const float* cls_b  = (const float*)d_in[8];
    float* out = (float*)d_out;

    unsigned short* u16 = (unsigned short*)d_ws;
    unsigned short* tbuf = u16;                    // 32*256*128 = 1048576
    unsigned short* hbuf = tbuf + 1048576;         // 32*256*128 = 1048576
    unsigned short* WP   = hbuf + 1048576;         // 16*256*64  = 262144
    unsigned short* Ut   = WP + 262144;            // 10*128*128 = 163840
    float* hwp  = (float*)(Ut + 163840);           // 8160*12
    float* twp  = hwp + 97920;
    float* tblp = twp + 97920;                     // 256*12

    hipLaunchKernelGGL(convert_wp, dim3(16), dim3(256), 0, stream,
                       head_w, tail_w, WP);
    hipLaunchKernelGGL(ht_mfma, dim3(255), dim3(512), 0, stream,
                       state, WP, U, wtab, head_b, tail_b, cls_w, cls_b,
                       Ut, hbuf, tbuf, hwp, twp, tblp);
    hipLaunchKernelGGL(main_mfma, dim3(8, 32), dim3(512), 0, stream,
                       hbuf, tbuf, Ut, hwp, twp, tblp, out);
}